// Round 1
// 509.934 us; speedup vs baseline: 1.0258x; 1.0258x over previous
//
#include <hip/hip_runtime.h>

#define B_N 2048
#define T_N 512
#define D_N 88
#define H_N 16
#define NEGF (-1e30f)
#define LN2F 0.69314718055994530942f

typedef __attribute__((ext_vector_type(8))) short short8;
typedef __attribute__((ext_vector_type(4))) short short4v;
typedef __attribute__((ext_vector_type(4))) float floatx4;

// ---------- DPP helpers (row_ror within 16-lane rows) ----------
template<int CTRL>
__device__ __forceinline__ float dppf(float x) {
    return __int_as_float(__builtin_amdgcn_update_dpp(
        0, __float_as_int(x), CTRL, 0xF, 0xF, false));
}

__device__ __forceinline__ float grp16_max(float v) {
    v = fmaxf(v, dppf<0x128>(v)); // ror8
    v = fmaxf(v, dppf<0x124>(v)); // ror4
    v = fmaxf(v, dppf<0x122>(v)); // ror2
    v = fmaxf(v, dppf<0x121>(v)); // ror1
    return v;
}
__device__ __forceinline__ float grp16_sum(float v) {
    v += dppf<0x128>(v);
    v += dppf<0x124>(v);
    v += dppf<0x122>(v);
    v += dppf<0x121>(v);
    return v;
}

__device__ __forceinline__ ushort bf16rne(float f) {
    unsigned u = __float_as_uint(f);
    u += 0x7FFFu + ((u >> 16) & 1u);
    return (ushort)(u >> 16);
}

// truncating pack of two f32 into {lo=bf16(x), hi=bf16(y)}
__device__ __forceinline__ unsigned packbf(float x, float y) {
    return (__float_as_uint(x) >> 16) | (__float_as_uint(y) & 0xFFFF0000u);
}

__device__ __forceinline__ float swz_xor16_f(float v) {
    return __int_as_float(
        __builtin_amdgcn_ds_swizzle(__float_as_int(v), 0x401F));
}

// one 16x16x16 bf16 MFMA step. Device-only conditional (no host-visible
// structure depends on __has_builtin).
__device__ __forceinline__ floatx4 mfma16(short4v a, short4v b) {
    floatx4 z = {0.f, 0.f, 0.f, 0.f};
#if __has_builtin(__builtin_amdgcn_mfma_f32_16x16x16bf16_1k)
    return __builtin_amdgcn_mfma_f32_16x16x16bf16_1k(a, b, z, 0, 0, 0);
#else
    floatx4 d;
    asm volatile("v_mfma_f32_16x16x16_bf16 %0, %1, %2, %3\n\t"
                 "s_nop 7\n\ts_nop 7"
                 : "=&v"(d) : "v"(a), "v"(b), "v"(z));
    return d;
#endif
}

// Self-calibrating A gather (fused-naive fallback only)
__device__ __forceinline__ void calib(const float* __restrict__ px, int h,
                                      float (&aro)[16]) {
    float idxf = (float)h;
    aro[0]  = px[h * 16 + h];
    aro[1]  = px[((int)dppf<0x121>(idxf)) * 16 + h];
    aro[2]  = px[((int)dppf<0x122>(idxf)) * 16 + h];
    aro[3]  = px[((int)dppf<0x123>(idxf)) * 16 + h];
    aro[4]  = px[((int)dppf<0x124>(idxf)) * 16 + h];
    aro[5]  = px[((int)dppf<0x125>(idxf)) * 16 + h];
    aro[6]  = px[((int)dppf<0x126>(idxf)) * 16 + h];
    aro[7]  = px[((int)dppf<0x127>(idxf)) * 16 + h];
    aro[8]  = px[((int)dppf<0x128>(idxf)) * 16 + h];
    aro[9]  = px[((int)dppf<0x129>(idxf)) * 16 + h];
    aro[10] = px[((int)dppf<0x12A>(idxf)) * 16 + h];
    aro[11] = px[((int)dppf<0x12B>(idxf)) * 16 + h];
    aro[12] = px[((int)dppf<0x12C>(idxf)) * 16 + h];
    aro[13] = px[((int)dppf<0x12D>(idxf)) * 16 + h];
    aro[14] = px[((int)dppf<0x12E>(idxf)) * 16 + h];
    aro[15] = px[((int)dppf<0x12F>(idxf)) * 16 + h];
}

__device__ __forceinline__ float matvec16(float p, const float (&aro)[16]) {
    float a0 = p * aro[0];
    float a1 = dppf<0x121>(p) * aro[1];
    float a2 = dppf<0x122>(p) * aro[2];
    float a3 = dppf<0x123>(p) * aro[3];
    a0 += dppf<0x124>(p) * aro[4];
    a1 += dppf<0x125>(p) * aro[5];
    a2 += dppf<0x126>(p) * aro[6];
    a3 += dppf<0x127>(p) * aro[7];
    a0 += dppf<0x128>(p) * aro[8];
    a1 += dppf<0x129>(p) * aro[9];
    a2 += dppf<0x12A>(p) * aro[10];
    a3 += dppf<0x12B>(p) * aro[11];
    a0 += dppf<0x12C>(p) * aro[12];
    a1 += dppf<0x12D>(p) * aro[13];
    a2 += dppf<0x12E>(p) * aro[14];
    a3 += dppf<0x12F>(p) * aro[15];
    return (a0 + a1) + (a2 + a3);
}

// log-domain step (fused-naive fallback only)
__device__ __forceinline__ void hmm_step(float& aRel, float& M, float emit2,
                                         bool valid, const float (&aro)[16]) {
    float p = exp2f(aRel);
    float s = matvec16(p, aro);
    float g = __log2f(s) + emit2;
    float mg = grp16_max(g);
    if (valid) { aRel = g - mg; M = M + mg; }
}

// ---------- kernel 0: pack B fragments + base + zero cSum ----------
// Widened to 16 blocks: the old single-block version serialized the
// stream for ~launch+work with 255/256 of one CU idle.
__global__ void hmm_prep(const float* __restrict__ probs_y,
                         ushort* __restrict__ bpack, float* __restrict__ base,
                         float* __restrict__ cSum) {
    int tid = blockIdx.x * 256 + threadIdx.x;    // 16*256 = 4096 threads
    for (int i = tid; i < 3 * 64 * 8; i += 4096) {
        int k = i >> 9;
        int l = (i >> 3) & 63;
        int j = i & 7;
        int kk = k * 32 + ((l >> 4) * 8) + j;
        int h = l & 15;
        ushort v = 0;
        if (kk < D_N) {
            float p = probs_y[h * D_N + kk];
            v = bf16rne(log2f(p) - log2f(1.0f - p));
        }
        bpack[i] = v;
    }
    for (int i = tid; i < B_N; i += 4096) cSum[i] = 0.0f;
    if (tid < H_N) {                              // block 0 only
        float s = 0.0f;
        for (int d = 0; d < D_N; ++d)
            s += log2f(1.0f - probs_y[tid * D_N + d]);
        base[tid] = s;
    }
}

// ---------- kernel 1: MFMA emission; w=exp2(e-c) bf16 [b][t][h] + csum ----------
__global__ __launch_bounds__(256) void hmm_emit(
    const float* __restrict__ seq, const int* __restrict__ lengths,
    const ushort* __restrict__ bpack, const float* __restrict__ base,
    ushort* __restrict__ wBuf, float* __restrict__ cSum) {
    int bid = blockIdx.x;
    int b = bid >> 3;
    int t0 = (bid & 7) * 64;
    int len = lengths[b];
    if (t0 >= len) return;                      // block-uniform early exit
    int lenLoc = min(len - t0, 64);             // live rows in this tile

    __shared__ ushort sA[64 * 104];             // bf16 rows, stride 104
    int tid = threadIdx.x;
    const float* gseq = seq + ((size_t)b * T_N + t0) * D_N;

    for (int f = tid; f < 768; f += 256) {
        if (f < 704) {                           // 64 rows x 11 chunks of 8 f32
            int r = f / 11;
            if (r < lenLoc) {                    // skip dead rows: saves HBM
                int c = f - r * 11;
                const float* gp = gseq + f * 8;  // f*8 == r*88 + c*8
                float4 v0 = *(const float4*)(gp);
                float4 v1 = *(const float4*)(gp + 4);
                uint4 w;
                w.x = (__float_as_uint(v0.x) >> 16) | (__float_as_uint(v0.y) & 0xFFFF0000u);
                w.y = (__float_as_uint(v0.z) >> 16) | (__float_as_uint(v0.w) & 0xFFFF0000u);
                w.z = (__float_as_uint(v1.x) >> 16) | (__float_as_uint(v1.y) & 0xFFFF0000u);
                w.w = (__float_as_uint(v1.z) >> 16) | (__float_as_uint(v1.w) & 0xFFFF0000u);
                *(uint4*)(&sA[r * 104 + c * 8]) = w;
            }
        } else {                                 // zero k-pad 88..95
            int r = f - 704;
            uint4 z; z.x = 0; z.y = 0; z.z = 0; z.w = 0;
            *(uint4*)(&sA[r * 104 + 88]) = z;
        }
    }
    __syncthreads();

    int l = tid & 63, w = tid >> 6;
    int q = l >> 4, h = l & 15;

    const short8* bp = (const short8*)bpack;
    short8 bf0 = bp[l];
    short8 bf1 = bp[64 + l];
    short8 bf2 = bp[128 + l];

    int arow = w * 16 + h;
    short8 af0 = *(const short8*)&sA[arow * 104 + 0  + q * 8];
    short8 af1 = *(const short8*)&sA[arow * 104 + 32 + q * 8];
    short8 af2 = *(const short8*)&sA[arow * 104 + 64 + q * 8];

    floatx4 acc = {0.f, 0.f, 0.f, 0.f};
    acc = __builtin_amdgcn_mfma_f32_16x16x32_bf16(af0, bf0, acc, 0, 0, 0);
    acc = __builtin_amdgcn_mfma_f32_16x16x32_bf16(af1, bf1, acc, 0, 0, 0);
    acc = __builtin_amdgcn_mfma_f32_16x16x32_bf16(af2, bf2, acc, 0, 0, 0);

    // C/D: col h = lane&15, row = q*4 + reg
    float bh = base[h];
    float e0 = acc[0] + bh, e1 = acc[1] + bh, e2 = acc[2] + bh, e3 = acc[3] + bh;
    float c0 = grp16_max(e0), c1 = grp16_max(e1);
    float c2 = grp16_max(e2), c3 = grp16_max(e3);

    int tRow = t0 + w * 16 + q * 4;
    // layout [b][t][h] for the chunk scan (unconditional within live tile)
    size_t wb = ((size_t)b * T_N + tRow) * H_N + h;
    wBuf[wb]      = bf16rne(exp2f(e0 - c0));
    wBuf[wb + 16] = bf16rne(exp2f(e1 - c1));
    wBuf[wb + 32] = bf16rne(exp2f(e2 - c2));
    wBuf[wb + 48] = bf16rne(exp2f(e3 - c3));

    // csum: masked sum of c over this wave's 16 rows, one atomic per wave
    float cs = 0.0f;
    if (tRow + 0 < len) cs += c0;
    if (tRow + 1 < len) cs += c1;
    if (tRow + 2 < len) cs += c2;
    if (tRow + 3 < len) cs += c3;
    cs += swz_xor16_f(cs);
    cs += __shfl_xor(cs, 32, 64);
    if (l == 0) atomicAdd(&cSum[b], cs);
}

// ---------- kernel 2a: chunked forward scan, Phase A ----------
// The recurrence alpha' = diag(w_t)·A^T·alpha is LINEAR, so the scan is a
// product of 16x16 matrices M_t = diag(w_t)·A^T — associative, hence
// chunk-parallel. One wave builds the product over one 64-step chunk of one
// sequence: P columns are the 16 basis vectors, each evolving exactly like
// the proven sequential alpha (same MFMA, same bf16 pack, same PER-COLUMN
// exponent renorm — numerics identical in structure). 16384 waves vs the old
// 128: latency fully hidden at 8 waves/SIMD.
// P stored f32 row-major [row=dest][col=src]; per-column log2-scales in Mbuf.
__global__ __launch_bounds__(256) void hmm_scanA(
    const float* __restrict__ px, const ushort* __restrict__ wBuf,
    const int* __restrict__ lengths,
    float* __restrict__ Pbuf, float* __restrict__ Mbuf) {
    int wid = blockIdx.x * 4 + (threadIdx.x >> 6);  // chunk id = b*8 + c
    int b = wid >> 3, c = wid & 7;
    int len = lengths[b];
    int t0 = c * 64;
    if (t0 >= len) return;                // dead chunk: never read by Phase B
    int tEnd = min(64, len - t0);         // wave-uniform loop bound

    int lane = threadIdx.x & 63;
    int s = lane & 15, q = lane >> 4;

    // A-operand: Aop[m=lane&15][k=q*4+j] = A[k][m]  (transition k -> m)
    short4v af;
#pragma unroll
    for (int j = 0; j < 4; ++j)
        af[j] = (short)bf16rne(px[(q * 4 + j) * 16 + s]);

    // P = I: p_j = P[row=q*4+j][col=s]
    float p0 = (q * 4 + 0 == s) ? 1.f : 0.f;
    float p1 = (q * 4 + 1 == s) ? 1.f : 0.f;
    float p2 = (q * 4 + 2 == s) ? 1.f : 0.f;
    float p3 = (q * 4 + 3 == s) ? 1.f : 0.f;
    unsigned bp0 = packbf(p0, p1), bp1 = packbf(p2, p3);
    float M = 0.f;                        // per-column log2 scale (uniform in q)

    const ushort4* wp = (const ushort4*)wBuf;
    size_t idx0 = ((size_t)b * T_N + t0) * 4 + q;   // [b][t0][q*4..q*4+3]
    ushort4 w4 = wp[idx0];                // t < len only: never reads poison

    for (int t = 0; t < tEnd; ++t) {
        // prefetch next step (last one lands at most 8B past wBuf -> Pbuf
        // region, in-bounds of ws, value unused)
        ushort4 wn = wp[idx0 + (size_t)(t + 1) * 4];
        float w0 = __uint_as_float((unsigned)w4.x << 16);
        float w1 = __uint_as_float((unsigned)w4.y << 16);
        float w2 = __uint_as_float((unsigned)w4.z << 16);
        float w3 = __uint_as_float((unsigned)w4.w << 16);
        union { unsigned u[2]; short4v v; } bu;
        bu.u[0] = bp0; bu.u[1] = bp1;
        floatx4 d = mfma16(af, bu.v);     // d[j] = (A^T P)[q*4+j][s]
        p0 = d[0] * w0; p1 = d[1] * w1; p2 = d[2] * w2; p3 = d[3] * w3;
        if ((t & 7) == 7) {               // immediate per-column renorm
            float mx = fmaxf(fmaxf(p0, p1), fmaxf(p2, p3));
            mx = fmaxf(mx, swz_xor16_f(mx));          // xor lane-bit 4
            mx = fmaxf(mx, __shfl_xor(mx, 32, 64));   // xor lane-bit 5
            unsigned ex = (__float_as_uint(mx) >> 23) & 0xFFu;
            float S = __uint_as_float((254u - ex) << 23);  // 2^(127-E)
            p0 *= S; p1 *= S; p2 *= S; p3 *= S;
            M += (float)((int)ex - 127);
        }
        bp0 = packbf(p0, p1); bp1 = packbf(p2, p3);
        w4 = wn;
    }

    // store P row-major: Pc[row*16+col]; lanes s are contiguous per (q,j)
    float* Pc = Pbuf + (size_t)wid * 256;
    Pc[(q * 4 + 0) * 16 + s] = p0;
    Pc[(q * 4 + 1) * 16 + s] = p1;
    Pc[(q * 4 + 2) * 16 + s] = p2;
    Pc[(q * 4 + 3) * 16 + s] = p3;
    if (q == 0) Mbuf[(size_t)wid * 16 + s] = M;
}

// ---------- kernel 2b: Phase B — compose chunk matrices, 1 wave = 1 seq ----------
// alpha starts as e0 (delta at state 0); per chunk: rescale alpha by the
// chunk's per-column scales in log2 domain, matvec against stored P, reduce.
__global__ __launch_bounds__(256) void hmm_scanB(
    const float* __restrict__ Pbuf, const float* __restrict__ Mbuf,
    const float* __restrict__ cSum, const int* __restrict__ lengths,
    const float* __restrict__ scale, float* __restrict__ out) {
    int b = blockIdx.x * 4 + (threadIdx.x >> 6);
    int lane = threadIdx.x & 63;
    int m = lane & 15, q = lane >> 4;
    int len = lengths[b];
    int nc = (len + 63) >> 6;             // live chunks

    float aval = (m == 0) ? 1.f : 0.f;    // alpha[m], replicated across q
    float Mrun = 0.f;

    for (int c = 0; c < nc; ++c) {
        size_t wid = (size_t)b * 8 + c;
        const float4 P4 = *(const float4*)(Pbuf + wid * 256 + m * 16 + q * 4);
        float Mc = Mbuf[wid * 16 + m];
        // t_m = Mc_m + log2(alpha[m]); renormalize in log2 domain
        float lm = (aval > 0.f) ? (Mc + __log2f(aval)) : -3e38f;
        float tmax = grp16_max(lm);       // max over m (replicated across q)
        float ain = exp2f(lm - tmax);     // alpha_in[m] in (0,1]
        Mrun += tmax;
        // gather alpha_in[k] for k = q*4+j (source lanes 0..15 hold m=k)
        float a0 = __shfl(ain, q * 4 + 0, 64);
        float a1 = __shfl(ain, q * 4 + 1, 64);
        float a2 = __shfl(ain, q * 4 + 2, 64);
        float a3 = __shfl(ain, q * 4 + 3, 64);
        float part = P4.x * a0 + P4.y * a1 + P4.z * a2 + P4.w * a3;
        part += swz_xor16_f(part);                 // reduce over lane-bit 4
        part += __shfl_xor(part, 32, 64);          // reduce over lane-bit 5
        aval = part;                               // alpha_next[m], repl. in q
    }
    float tot = grp16_sum(aval);          // sum over 16 states
    float ll = LN2F * (cSum[b] + Mrun + __log2f(tot));
    if (lane == 0) out[b] = scale[0] * ll;
}

// ---------- fallback: fused naive (if ws too small) ----------
__global__ __launch_bounds__(64) void hmm_fused_naive(
    const float* __restrict__ seq, const float* __restrict__ px,
    const float* __restrict__ py, const float* __restrict__ sc,
    const int* __restrict__ lengths, float* __restrict__ out) {
    int lane = threadIdx.x;
    int sl = lane >> 4, h = lane & 15;
    int b0 = blockIdx.x * 4;
    int b = b0 + sl;
    int len = lengths[b];

    float aro[16];
    calib(px, h, aro);

    float wreg[88];
    float b2 = 0.0f;
#pragma unroll
    for (int d = 0; d < D_N; ++d) {
        float p = py[h * D_N + d];
        float l1 = log2f(1.0f - p);
        wreg[d] = log2f(p) - l1;
        b2 += l1;
    }
    int wmax = max(max(lengths[b0], lengths[b0 + 1]),
                   max(lengths[b0 + 2], lengths[b0 + 3]));

    float aRel = (h == 0) ? 0.0f : NEGF;
    float M = 0.0f;
    for (int t = 0; t < wmax; ++t) {
        const float4* sp = (const float4*)(seq + ((size_t)b * T_N + t) * D_N);
        float e = b2;
#pragma unroll
        for (int j = 0; j < 22; ++j) {
            float4 v = sp[j];
            e += v.x * wreg[4 * j] + v.y * wreg[4 * j + 1] +
                 v.z * wreg[4 * j + 2] + v.w * wreg[4 * j + 3];
        }
        hmm_step(aRel, M, e, t < len, aro);
    }
    float pf = exp2f(aRel);
    float s = grp16_sum(pf);
    if (h == 0)
        out[b] = sc[0] * (LN2F * (M + __log2f(s)));
}

extern "C" void kernel_launch(void* const* d_in, const int* in_sizes, int n_in,
                              void* d_out, int out_size, void* d_ws,
                              size_t ws_size, hipStream_t stream) {
    const float* seq = (const float*)d_in[0];   // [B,T,D] f32
    const float* px  = (const float*)d_in[1];   // [H,H]   f32 (linear probs)
    const float* py  = (const float*)d_in[2];   // [H,D]   f32
    const float* sc  = (const float*)d_in[3];   // [1]     f32
    const int*   len = (const int*)d_in[4];     // [B]     i32
    float* out = (float*)d_out;                 // [B]     f32

    size_t w_bytes = (size_t)B_N * T_N * H_N * 2;     // wBuf: 33.55 MB
    size_t p_bytes = (size_t)B_N * 8 * 256 * 4;       // Pbuf: 16.78 MB
    size_t m_bytes = (size_t)B_N * 8 * 16 * 4;        // Mbuf:  1.05 MB
    size_t need = w_bytes + p_bytes + m_bytes + B_N * 4 + 64 + 3072 + 4096;
    if (ws_size >= need) {
        char* ws = (char*)d_ws;
        ushort* wBuf  = (ushort*)ws;
        float*  Pbuf  = (float*)(ws + w_bytes);
        float*  Mbuf  = (float*)(ws + w_bytes + p_bytes);
        float*  cSum  = (float*)(ws + w_bytes + p_bytes + m_bytes);
        float*  base  = cSum + B_N;
        ushort* bpack = (ushort*)(base + 16);
        hmm_prep<<<16, 256, 0, stream>>>(py, bpack, base, cSum);
        hmm_emit<<<B_N * 8, 256, 0, stream>>>(seq, len, bpack, base, wBuf, cSum);
        hmm_scanA<<<B_N * 8 / 4, 256, 0, stream>>>(px, wBuf, len, Pbuf, Mbuf);
        hmm_scanB<<<B_N / 4, 256, 0, stream>>>(Pbuf, Mbuf, cSum, len, sc, out);
    } else {
        hmm_fused_naive<<<B_N / 4, 64, 0, stream>>>(seq, px, py, sc, len, out);
    }
}

// Round 2
// 497.568 us; speedup vs baseline: 1.0513x; 1.0249x over previous
//
#include <hip/hip_runtime.h>

#define B_N 2048
#define T_N 512
#define D_N 88
#define H_N 16
#define NEGF (-1e30f)
#define LN2F 0.69314718055994530942f

typedef __attribute__((ext_vector_type(8))) short short8;
typedef __attribute__((ext_vector_type(4))) short short4v;
typedef __attribute__((ext_vector_type(4))) float floatx4;

// ---------- DPP helpers (row_ror within 16-lane rows) ----------
template<int CTRL>
__device__ __forceinline__ float dppf(float x) {
    return __int_as_float(__builtin_amdgcn_update_dpp(
        0, __float_as_int(x), CTRL, 0xF, 0xF, false));
}

__device__ __forceinline__ float grp16_max(float v) {
    v = fmaxf(v, dppf<0x128>(v)); // ror8
    v = fmaxf(v, dppf<0x124>(v)); // ror4
    v = fmaxf(v, dppf<0x122>(v)); // ror2
    v = fmaxf(v, dppf<0x121>(v)); // ror1
    return v;
}
__device__ __forceinline__ float grp16_sum(float v) {
    v += dppf<0x128>(v);
    v += dppf<0x124>(v);
    v += dppf<0x122>(v);
    v += dppf<0x121>(v);
    return v;
}

__device__ __forceinline__ ushort bf16rne(float f) {
    unsigned u = __float_as_uint(f);
    u += 0x7FFFu + ((u >> 16) & 1u);
    return (ushort)(u >> 16);
}

// truncating pack of two f32 into {lo=bf16(x), hi=bf16(y)}
__device__ __forceinline__ unsigned packbf(float x, float y) {
    return (__float_as_uint(x) >> 16) | (__float_as_uint(y) & 0xFFFF0000u);
}

__device__ __forceinline__ float swz_xor16_f(float v) {
    return __int_as_float(
        __builtin_amdgcn_ds_swizzle(__float_as_int(v), 0x401F));
}

// one 16x16x16 bf16 MFMA step. Device-only conditional.
__device__ __forceinline__ floatx4 mfma16(short4v a, short4v b) {
    floatx4 z = {0.f, 0.f, 0.f, 0.f};
#if __has_builtin(__builtin_amdgcn_mfma_f32_16x16x16bf16_1k)
    return __builtin_amdgcn_mfma_f32_16x16x16bf16_1k(a, b, z, 0, 0, 0);
#else
    floatx4 d;
    asm volatile("v_mfma_f32_16x16x16_bf16 %0, %1, %2, %3\n\t"
                 "s_nop 7\n\ts_nop 7"
                 : "=&v"(d) : "v"(a), "v"(b), "v"(z));
    return d;
#endif
}

// Self-calibrating A gather (fused-naive fallback only)
__device__ __forceinline__ void calib(const float* __restrict__ px, int h,
                                      float (&aro)[16]) {
    float idxf = (float)h;
    aro[0]  = px[h * 16 + h];
    aro[1]  = px[((int)dppf<0x121>(idxf)) * 16 + h];
    aro[2]  = px[((int)dppf<0x122>(idxf)) * 16 + h];
    aro[3]  = px[((int)dppf<0x123>(idxf)) * 16 + h];
    aro[4]  = px[((int)dppf<0x124>(idxf)) * 16 + h];
    aro[5]  = px[((int)dppf<0x125>(idxf)) * 16 + h];
    aro[6]  = px[((int)dppf<0x126>(idxf)) * 16 + h];
    aro[7]  = px[((int)dppf<0x127>(idxf)) * 16 + h];
    aro[8]  = px[((int)dppf<0x128>(idxf)) * 16 + h];
    aro[9]  = px[((int)dppf<0x129>(idxf)) * 16 + h];
    aro[10] = px[((int)dppf<0x12A>(idxf)) * 16 + h];
    aro[11] = px[((int)dppf<0x12B>(idxf)) * 16 + h];
    aro[12] = px[((int)dppf<0x12C>(idxf)) * 16 + h];
    aro[13] = px[((int)dppf<0x12D>(idxf)) * 16 + h];
    aro[14] = px[((int)dppf<0x12E>(idxf)) * 16 + h];
    aro[15] = px[((int)dppf<0x12F>(idxf)) * 16 + h];
}

__device__ __forceinline__ float matvec16(float p, const float (&aro)[16]) {
    float a0 = p * aro[0];
    float a1 = dppf<0x121>(p) * aro[1];
    float a2 = dppf<0x122>(p) * aro[2];
    float a3 = dppf<0x123>(p) * aro[3];
    a0 += dppf<0x124>(p) * aro[4];
    a1 += dppf<0x125>(p) * aro[5];
    a2 += dppf<0x126>(p) * aro[6];
    a3 += dppf<0x127>(p) * aro[7];
    a0 += dppf<0x128>(p) * aro[8];
    a1 += dppf<0x129>(p) * aro[9];
    a2 += dppf<0x12A>(p) * aro[10];
    a3 += dppf<0x12B>(p) * aro[11];
    a0 += dppf<0x12C>(p) * aro[12];
    a1 += dppf<0x12D>(p) * aro[13];
    a2 += dppf<0x12E>(p) * aro[14];
    a3 += dppf<0x12F>(p) * aro[15];
    return (a0 + a1) + (a2 + a3);
}

// log-domain step (fused-naive fallback only)
__device__ __forceinline__ void hmm_step(float& aRel, float& M, float emit2,
                                         bool valid, const float (&aro)[16]) {
    float p = exp2f(aRel);
    float s = matvec16(p, aro);
    float g = __log2f(s) + emit2;
    float mg = grp16_max(g);
    if (valid) { aRel = g - mg; M = M + mg; }
}

// ---------- kernel 0: pack B fragments + base + zero cSum ----------
__global__ void hmm_prep(const float* __restrict__ probs_y,
                         ushort* __restrict__ bpack, float* __restrict__ base,
                         float* __restrict__ cSum) {
    int tid = blockIdx.x * 256 + threadIdx.x;    // 16*256 = 4096 threads
    for (int i = tid; i < 3 * 64 * 8; i += 4096) {
        int k = i >> 9;
        int l = (i >> 3) & 63;
        int j = i & 7;
        int kk = k * 32 + ((l >> 4) * 8) + j;
        int h = l & 15;
        ushort v = 0;
        if (kk < D_N) {
            float p = probs_y[h * D_N + kk];
            v = bf16rne(log2f(p) - log2f(1.0f - p));
        }
        bpack[i] = v;
    }
    for (int i = tid; i < B_N; i += 4096) cSum[i] = 0.0f;
    if (tid < H_N) {                              // block 0 only
        float s = 0.0f;
        for (int d = 0; d < D_N; ++d)
            s += log2f(1.0f - probs_y[tid * D_N + d]);
        base[tid] = s;
    }
}

// ---------- kernel 1: FUSED emission + chunk-matrix scan ----------
// One block = one (b, 64-step chunk) tile. Phase 1 (4 waves): MFMA emission
// exactly as before, but w = exp2(e-c) goes to LDS (f32, stride 20: writes
// 2-way aliased = free, reads 16-lane broadcast, 16B-aligned) instead of a
// 19 MB HBM wBuf that the old scanA immediately re-read (~38 MB round-trip
// + one launch saved). Phase 2 (wave 0 only): the proven chunk-matrix
// product, reading w from LDS with next-step prefetch above the MFMA.
__global__ __launch_bounds__(256) void hmm_emitscan(
    const float* __restrict__ seq, const int* __restrict__ lengths,
    const ushort* __restrict__ bpack, const float* __restrict__ base,
    const float* __restrict__ px,
    float* __restrict__ Pbuf, float* __restrict__ Mbuf,
    float* __restrict__ cSum) {
    int bid = blockIdx.x;                        // bid = b*8 + c
    int b = bid >> 3;
    int t0 = (bid & 7) * 64;
    int len = lengths[b];
    if (t0 >= len) return;                       // dead chunk: block-uniform
    int lenLoc = min(len - t0, 64);              // live rows in this tile

    __shared__ ushort sA[64 * 104];              // bf16 seq rows, stride 104
    __shared__ float wS[64 * 20];                // w[t][h], stride 20 f32
    int tid = threadIdx.x;
    const float* gseq = seq + ((size_t)b * T_N + t0) * D_N;

    for (int f = tid; f < 768; f += 256) {
        if (f < 704) {                           // 64 rows x 11 chunks of 8 f32
            int r = f / 11;
            if (r < lenLoc) {                    // skip dead rows: saves HBM
                int c = f - r * 11;
                const float* gp = gseq + f * 8;  // f*8 == r*88 + c*8
                float4 v0 = *(const float4*)(gp);
                float4 v1 = *(const float4*)(gp + 4);
                uint4 wv;
                wv.x = (__float_as_uint(v0.x) >> 16) | (__float_as_uint(v0.y) & 0xFFFF0000u);
                wv.y = (__float_as_uint(v0.z) >> 16) | (__float_as_uint(v0.w) & 0xFFFF0000u);
                wv.z = (__float_as_uint(v1.x) >> 16) | (__float_as_uint(v1.y) & 0xFFFF0000u);
                wv.w = (__float_as_uint(v1.z) >> 16) | (__float_as_uint(v1.w) & 0xFFFF0000u);
                *(uint4*)(&sA[r * 104 + c * 8]) = wv;
            }
        } else {                                 // zero k-pad 88..95
            int r = f - 704;
            uint4 z; z.x = 0; z.y = 0; z.z = 0; z.w = 0;
            *(uint4*)(&sA[r * 104 + 88]) = z;
        }
    }
    __syncthreads();

    int l = tid & 63, w = tid >> 6;
    int q = l >> 4, h = l & 15;

    const short8* bp = (const short8*)bpack;
    short8 bf0 = bp[l];
    short8 bf1 = bp[64 + l];
    short8 bf2 = bp[128 + l];

    int arow = w * 16 + h;
    short8 af0 = *(const short8*)&sA[arow * 104 + 0  + q * 8];
    short8 af1 = *(const short8*)&sA[arow * 104 + 32 + q * 8];
    short8 af2 = *(const short8*)&sA[arow * 104 + 64 + q * 8];

    floatx4 acc = {0.f, 0.f, 0.f, 0.f};
    acc = __builtin_amdgcn_mfma_f32_16x16x32_bf16(af0, bf0, acc, 0, 0, 0);
    acc = __builtin_amdgcn_mfma_f32_16x16x32_bf16(af1, bf1, acc, 0, 0, 0);
    acc = __builtin_amdgcn_mfma_f32_16x16x32_bf16(af2, bf2, acc, 0, 0, 0);

    // C/D: col h = lane&15, row = q*4 + reg
    float bh = base[h];
    float e0 = acc[0] + bh, e1 = acc[1] + bh, e2 = acc[2] + bh, e3 = acc[3] + bh;
    float c0 = grp16_max(e0), c1 = grp16_max(e1);
    float c2 = grp16_max(e2), c3 = grp16_max(e3);

    int tLoc = w * 16 + q * 4;                   // local t of first row
    // dead rows (>= lenLoc) may hold garbage/NaN: never read by the scan,
    // and masked out of cs below — same invariant the split version had.
    wS[(tLoc + 0) * 20 + h] = exp2f(e0 - c0);
    wS[(tLoc + 1) * 20 + h] = exp2f(e1 - c1);
    wS[(tLoc + 2) * 20 + h] = exp2f(e2 - c2);
    wS[(tLoc + 3) * 20 + h] = exp2f(e3 - c3);

    // csum: masked sum of c over this wave's 16 rows, one atomic per wave
    int tg = t0 + tLoc;
    float cs = 0.0f;
    if (tg + 0 < len) cs += c0;
    if (tg + 1 < len) cs += c1;
    if (tg + 2 < len) cs += c2;
    if (tg + 3 < len) cs += c3;
    cs += swz_xor16_f(cs);
    cs += __shfl_xor(cs, 32, 64);
    if (l == 0) atomicAdd(&cSum[b], cs);

    __syncthreads();                             // wS visible to wave 0
    if (w != 0) return;

    // ---- Phase 2: chunk matrix product (wave 0) ----
    int s = h;                                   // lane&15 = column
    // A-operand: Aop[m=lane&15][k=q*4+j] = A[k][m]  (transition k -> m)
    short4v af;
#pragma unroll
    for (int j = 0; j < 4; ++j)
        af[j] = (short)bf16rne(px[(q * 4 + j) * 16 + s]);

    // P = I: p_j = P[row=q*4+j][col=s]
    float p0 = (q * 4 + 0 == s) ? 1.f : 0.f;
    float p1 = (q * 4 + 1 == s) ? 1.f : 0.f;
    float p2 = (q * 4 + 2 == s) ? 1.f : 0.f;
    float p3 = (q * 4 + 3 == s) ? 1.f : 0.f;
    unsigned bp0 = packbf(p0, p1), bp1 = packbf(p2, p3);
    float M = 0.f;                               // per-column log2 scale

    float4 w4 = *(const float4*)&wS[q * 4];      // t = 0
    for (int t = 0; t < lenLoc; ++t) {
        int tn = (t + 1 < 64) ? t + 1 : 63;      // clamp: stay in wS
        float4 wn = *(const float4*)&wS[tn * 20 + q * 4];   // prefetch
        union { unsigned u[2]; short4v v; } bu;
        bu.u[0] = bp0; bu.u[1] = bp1;
        floatx4 d = mfma16(af, bu.v);            // d[j] = (A^T P)[q*4+j][s]
        p0 = d[0] * w4.x; p1 = d[1] * w4.y; p2 = d[2] * w4.z; p3 = d[3] * w4.w;
        if ((t & 7) == 7) {                      // per-column exponent renorm
            float mx = fmaxf(fmaxf(p0, p1), fmaxf(p2, p3));
            mx = fmaxf(mx, swz_xor16_f(mx));          // xor lane-bit 4
            mx = fmaxf(mx, __shfl_xor(mx, 32, 64));   // xor lane-bit 5
            unsigned ex = (__float_as_uint(mx) >> 23) & 0xFFu;
            float S = __uint_as_float((254u - ex) << 23);  // 2^(127-E)
            p0 *= S; p1 *= S; p2 *= S; p3 *= S;
            M += (float)((int)ex - 127);
        }
        bp0 = packbf(p0, p1); bp1 = packbf(p2, p3);
        w4 = wn;
    }

    // store P row-major: Pc[row*16+col]; lanes s contiguous per (q,j)
    float* Pc = Pbuf + (size_t)bid * 256;
    Pc[(q * 4 + 0) * 16 + s] = p0;
    Pc[(q * 4 + 1) * 16 + s] = p1;
    Pc[(q * 4 + 2) * 16 + s] = p2;
    Pc[(q * 4 + 3) * 16 + s] = p3;
    if (q == 0) Mbuf[(size_t)bid * 16 + s] = M;
}

// ---------- kernel 2: compose chunk matrices, 1 wave = 1 seq ----------
__global__ __launch_bounds__(256) void hmm_scanB(
    const float* __restrict__ Pbuf, const float* __restrict__ Mbuf,
    const float* __restrict__ cSum, const int* __restrict__ lengths,
    const float* __restrict__ scale, float* __restrict__ out) {
    int b = blockIdx.x * 4 + (threadIdx.x >> 6);
    int lane = threadIdx.x & 63;
    int m = lane & 15, q = lane >> 4;
    int len = lengths[b];
    int nc = (len + 63) >> 6;             // live chunks

    float aval = (m == 0) ? 1.f : 0.f;    // alpha[m], replicated across q
    float Mrun = 0.f;

    for (int c = 0; c < nc; ++c) {
        size_t wid = (size_t)b * 8 + c;
        const float4 P4 = *(const float4*)(Pbuf + wid * 256 + m * 16 + q * 4);
        float Mc = Mbuf[wid * 16 + m];
        // t_m = Mc_m + log2(alpha[m]); renormalize in log2 domain
        float lm = (aval > 0.f) ? (Mc + __log2f(aval)) : -3e38f;
        float tmax = grp16_max(lm);       // max over m (replicated across q)
        float ain = exp2f(lm - tmax);     // alpha_in[m] in (0,1]
        Mrun += tmax;
        // gather alpha_in[k] for k = q*4+j (source lanes 0..15 hold m=k)
        float a0 = __shfl(ain, q * 4 + 0, 64);
        float a1 = __shfl(ain, q * 4 + 1, 64);
        float a2 = __shfl(ain, q * 4 + 2, 64);
        float a3 = __shfl(ain, q * 4 + 3, 64);
        float part = P4.x * a0 + P4.y * a1 + P4.z * a2 + P4.w * a3;
        part += swz_xor16_f(part);                 // reduce over lane-bit 4
        part += __shfl_xor(part, 32, 64);          // reduce over lane-bit 5
        aval = part;                               // alpha_next[m], repl. in q
    }
    float tot = grp16_sum(aval);          // sum over 16 states
    float ll = LN2F * (cSum[b] + Mrun + __log2f(tot));
    if (lane == 0) out[b] = scale[0] * ll;
}

// ---------- fallback: fused naive (if ws too small) ----------
__global__ __launch_bounds__(64) void hmm_fused_naive(
    const float* __restrict__ seq, const float* __restrict__ px,
    const float* __restrict__ py, const float* __restrict__ sc,
    const int* __restrict__ lengths, float* __restrict__ out) {
    int lane = threadIdx.x;
    int sl = lane >> 4, h = lane & 15;
    int b0 = blockIdx.x * 4;
    int b = b0 + sl;
    int len = lengths[b];

    float aro[16];
    calib(px, h, aro);

    float wreg[88];
    float b2 = 0.0f;
#pragma unroll
    for (int d = 0; d < D_N; ++d) {
        float p = py[h * D_N + d];
        float l1 = log2f(1.0f - p);
        wreg[d] = log2f(p) - l1;
        b2 += l1;
    }
    int wmax = max(max(lengths[b0], lengths[b0 + 1]),
                   max(lengths[b0 + 2], lengths[b0 + 3]));

    float aRel = (h == 0) ? 0.0f : NEGF;
    float M = 0.0f;
    for (int t = 0; t < wmax; ++t) {
        const float4* sp = (const float4*)(seq + ((size_t)b * T_N + t) * D_N);
        float e = b2;
#pragma unroll
        for (int j = 0; j < 22; ++j) {
            float4 v = sp[j];
            e += v.x * wreg[4 * j] + v.y * wreg[4 * j + 1] +
                 v.z * wreg[4 * j + 2] + v.w * wreg[4 * j + 3];
        }
        hmm_step(aRel, M, e, t < len, aro);
    }
    float pf = exp2f(aRel);
    float s = grp16_sum(pf);
    if (h == 0)
        out[b] = sc[0] * (LN2F * (M + __log2f(s)));
}

extern "C" void kernel_launch(void* const* d_in, const int* in_sizes, int n_in,
                              void* d_out, int out_size, void* d_ws,
                              size_t ws_size, hipStream_t stream) {
    const float* seq = (const float*)d_in[0];   // [B,T,D] f32
    const float* px  = (const float*)d_in[1];   // [H,H]   f32 (linear probs)
    const float* py  = (const float*)d_in[2];   // [H,D]   f32
    const float* sc  = (const float*)d_in[3];   // [1]     f32
    const int*   len = (const int*)d_in[4];     // [B]     i32
    float* out = (float*)d_out;                 // [B]     f32

    size_t p_bytes = (size_t)B_N * 8 * 256 * 4;       // Pbuf: 16.78 MB
    size_t m_bytes = (size_t)B_N * 8 * 16 * 4;        // Mbuf:  1.05 MB
    size_t need = p_bytes + m_bytes + B_N * 4 + 64 + 3072 + 4096;
    if (ws_size >= need) {
        char* ws = (char*)d_ws;
        float*  Pbuf  = (float*)ws;
        float*  Mbuf  = (float*)(ws + p_bytes);
        float*  cSum  = (float*)(ws + p_bytes + m_bytes);
        float*  base  = cSum + B_N;
        ushort* bpack = (ushort*)(base + 16);
        hmm_prep<<<16, 256, 0, stream>>>(py, bpack, base, cSum);
        hmm_emitscan<<<B_N * 8, 256, 0, stream>>>(seq, len, bpack, base, px,
                                                  Pbuf, Mbuf, cSum);
        hmm_scanB<<<B_N / 4, 256, 0, stream>>>(Pbuf, Mbuf, cSum, len, sc, out);
    } else {
        hmm_fused_naive<<<B_N / 4, 64, 0, stream>>>(seq, px, py, sc, len, out);
    }
}